// Round 9
// baseline (169.270 us; speedup 1.0000x reference)
//
#include <hip/hip_runtime.h>
#include <math.h>

// DistanceLoss — y_pred (8,2,512,512) f32, y_true (8,2,512,512) f32 -> scalar f32.
// loss = mean[(1 + EDT(y_true)/511) * (softmax(y_pred,C=2) - y_true)^2]
// Two dispatches: rows (1D EDT scan, also zeroes counter) + cols (windowed
// exact column envelope + fused loss + last-block reduction).

#define H 512
#define W 512
#define NIMG 16
#define HW (H * W)
#define RW 5                       // exact window radius; certified + fallback
#define SEG 8                      // output rows per thread (cols kernel)
#define HALO (SEG + 2 * RW)        // 18 halo rows
#define JT 256                     // columns per block
#define NBLK (NIMG * (H / SEG) * (W / JT))   // 2048 blocks

static __device__ __forceinline__ float fast_exp2(float x) {
#if __has_builtin(__builtin_amdgcn_exp2f)
    return __builtin_amdgcn_exp2f(x);
#else
    return exp2f(x);
#endif
}
static __device__ __forceinline__ float fast_rcp(float x) {
#if __has_builtin(__builtin_amdgcn_rcpf)
    return __builtin_amdgcn_rcpf(x);
#else
    return 1.0f / x;
#endif
}

// ---------------------------------------------------------------------------
// Pass 1 (validated, absmax 0.0): per-row 1D width-distance squared.
// One wave per row, 8 contiguous elements per lane. Also zeroes the counter.
// ---------------------------------------------------------------------------
__global__ __launch_bounds__(256) void edt_rows_kernel(const float* __restrict__ yt,
                                                       float* __restrict__ d1sq,
                                                       unsigned int* __restrict__ counter) {
    if (blockIdx.x == 0 && threadIdx.x == 0) *counter = 0u;

    int wid = blockIdx.x * 4 + (threadIdx.x >> 6);
    int lane = threadIdx.x & 63;
    int img = wid >> 9;
    int row = wid & (H - 1);

    const float* rp = yt + ((size_t)img * H + row) * W;
    int k0 = lane * 8;
    float4 va = *reinterpret_cast<const float4*>(rp + k0);
    float4 vb = *reinterpret_cast<const float4*>(rp + k0 + 4);
    float g[8] = { va.x, va.y, va.z, va.w, vb.x, vb.y, vb.z, vb.w };
    const float INF = 1024.0f;
    #pragma unroll
    for (int t = 0; t < 8; ++t) g[t] = (g[t] > 0.5f) ? 0.0f : INF;

    const float BIG = 3.0e38f;
    float pm[8], sm[8];

    float run = BIG;
    #pragma unroll
    for (int t = 0; t < 8; ++t) {
        run = fminf(run, g[t] - (float)(k0 + t));
        pm[t] = run;
    }
    float incl = run;
    #pragma unroll
    for (int d = 1; d < 64; d <<= 1) {
        float o = __shfl_up(incl, d);
        if (lane >= d) incl = fminf(incl, o);
    }
    float excl = __shfl_up(incl, 1);
    if (lane == 0) excl = BIG;

    run = BIG;
    #pragma unroll
    for (int t = 7; t >= 0; --t) {
        run = fminf(run, g[t] + (float)(k0 + t));
        sm[t] = run;
    }
    float incl2 = run;
    #pragma unroll
    for (int d = 1; d < 64; d <<= 1) {
        float o = __shfl_down(incl2, d);
        if (lane < 64 - d) incl2 = fminf(incl2, o);
    }
    float excl2 = __shfl_down(incl2, 1);
    if (lane == 63) excl2 = BIG;

    float out[8];
    #pragma unroll
    for (int t = 0; t < 8; ++t) {
        float kf = (float)(k0 + t);
        float f = kf + fminf(excl, pm[t]);
        float b = -kf + fminf(excl2, sm[t]);
        float d = fminf(f, b);
        out[t] = d * d;              // exact integer in fp32
    }
    float* op = d1sq + (size_t)img * HW + (size_t)row * W + k0;
    *reinterpret_cast<float4*>(op)     = make_float4(out[0], out[1], out[2], out[3]);
    *reinterpret_cast<float4*>(op + 4) = make_float4(out[4], out[5], out[6], out[7]);
}

// ---------------------------------------------------------------------------
// Pass 2: LDS-free windowed exact column envelope + fused loss + last-block
// reduction. Per thread: one column x SEG rows; HALO independent coalesced
// global loads. Window offsets are compile-time constants (RW-k)^2, paired
// symmetrically (min(w[-k],w[+k])+k^2). Certification: window min <= (RW+1)^2
// guarantees global optimality; else exact full-column fallback (dead here).
// Epilogue: softmax(2ch) == sigmoid -> 1 exp2 + 1 rcp per pixel.
// ---------------------------------------------------------------------------
__global__ __launch_bounds__(256) void edt_cols_loss_kernel(
        const float* __restrict__ yp, const float* __restrict__ yt,
        const float* __restrict__ d1sq, double* __restrict__ part,
        unsigned int* __restrict__ counter, float* __restrict__ out) {
    __shared__ double wsum[4];
    __shared__ int lastf;

    const int tid  = threadIdx.x;
    const int lane = tid & 63;
    const int wv   = tid >> 6;
    const int j    = blockIdx.x * JT + tid;
    const int i0   = blockIdx.y * SEG;
    const int img  = blockIdx.z;
    const int bid  = (blockIdx.z * gridDim.y + blockIdx.y) * gridDim.x + blockIdx.x;

    const float BIG = 3.0e38f;
    const float* dp = d1sq + (size_t)img * HW;

    float w[HALO];
    #pragma unroll
    for (int k = 0; k < HALO; ++k) {
        int ip = i0 - RW + k;
        w[k] = (ip >= 0 && ip < H) ? dp[ip * W + j] : BIG;
    }

    float mn[SEG];
    #pragma unroll
    for (int m = 0; m < SEG; ++m) {
        float a1 = fminf(w[m + 4], w[m + 6]) + 1.0f;
        float a2 = fminf(w[m + 3], w[m + 7]) + 4.0f;
        float a3 = fminf(w[m + 2], w[m + 8]) + 9.0f;
        float a4 = fminf(w[m + 1], w[m + 9]) + 16.0f;
        float a5 = fminf(w[m + 0], w[m + 10]) + 25.0f;
        mn[m] = fminf(fminf(fminf(w[m + 5], a1), fminf(a2, a3)), fminf(a4, a5));
    }

    bool need = false;
    #pragma unroll
    for (int m = 0; m < SEG; ++m) need |= (mn[m] > 36.0f);
    if (__any(need)) {          // exact fallback — provably dead for this input
        for (int ip = 0; ip < H; ++ip) {
            float v = dp[ip * W + j];
            #pragma unroll
            for (int m = 0; m < SEG; ++m) {
                int d = (i0 + m) - ip;
                mn[m] = fminf(mn[m], v + (float)(d * d));
            }
        }
    }

    // ---- fused loss epilogue: p = sigmoid(x_c - x_o) via exp2 + rcp ----
    const int n = img >> 1;
    const int c = img & 1;
    const float* ypc = yp + (size_t)(n * 2 + c) * HW;
    const float* ypo = yp + (size_t)(n * 2 + (1 - c)) * HW;
    const float* ytc = yt + (size_t)img * HW;
    const float LOG2E = 1.44269504088896340736f;

    double local = 0.0;
    #pragma unroll
    for (int m = 0; m < SEG; ++m) {
        int idx = (i0 + m) * W + j;
        float dmv = sqrtf(mn[m]) * (1.0f / 511.0f);
        float d  = ypo[idx] - ypc[idx];
        float e  = fast_exp2(d * LOG2E);
        float p  = fast_rcp(1.0f + e);
        float df = p - ytc[idx];
        local += (double)((1.0f + dmv) * (df * df));
    }

    #pragma unroll
    for (int d = 32; d > 0; d >>= 1) local += __shfl_down(local, d);
    if (lane == 0) wsum[wv] = local;
    __syncthreads();

    if (tid == 0) {
        double s = wsum[0] + wsum[1] + wsum[2] + wsum[3];
        __hip_atomic_store(&part[bid], s, __ATOMIC_RELEASE, __HIP_MEMORY_SCOPE_AGENT);
        unsigned int old = __hip_atomic_fetch_add(counter, 1u, __ATOMIC_ACQ_REL,
                                                  __HIP_MEMORY_SCOPE_AGENT);
        lastf = (old == NBLK - 1) ? 1 : 0;
    }
    __syncthreads();

    if (lastf) {   // last arriving block reduces all 2048 partials
        double v = 0.0;
        for (int q = tid; q < NBLK; q += 256)
            v += __hip_atomic_load(&part[q], __ATOMIC_ACQUIRE, __HIP_MEMORY_SCOPE_AGENT);
        #pragma unroll
        for (int d = 32; d > 0; d >>= 1) v += __shfl_down(v, d);
        if (lane == 0) wsum[wv] = v;
        __syncthreads();
        if (tid == 0)
            out[0] = (float)((wsum[0] + wsum[1] + wsum[2] + wsum[3]) / (double)(NIMG * HW));
    }
}

extern "C" void kernel_launch(void* const* d_in, const int* in_sizes, int n_in,
                              void* d_out, int out_size, void* d_ws, size_t ws_size,
                              hipStream_t stream) {
    const float* y_pred = (const float*)d_in[0];
    const float* y_true = (const float*)d_in[1];
    float* out = (float*)d_out;

    unsigned int* counter = (unsigned int*)d_ws;
    double* part = (double*)((char*)d_ws + 4096);       // 2048 doubles
    float*  d1sq = (float*)((char*)d_ws + 32768);       // 16.8 MB

    edt_rows_kernel<<<dim3(NIMG * H / 4), 256, 0, stream>>>(y_true, d1sq, counter);
    edt_cols_loss_kernel<<<dim3(W / JT, H / SEG, NIMG), 256, 0, stream>>>(
        y_pred, y_true, d1sq, part, counter, out);
}

// Round 10
// 86.362 us; speedup vs baseline: 1.9600x; 1.9600x over previous
//
#include <hip/hip_runtime.h>
#include <math.h>

// DistanceLoss — y_pred (8,2,512,512) f32, y_true (8,2,512,512) f32 -> scalar f32.
// loss = mean[(1 + EDT(y_true)/511) * (softmax(y_pred,C=2) - y_true)^2]
// Three dispatches, NO device-scope atomics (round-9 lesson: per-block
// agent-scope release/acquire = L2 maintenance storm on multi-XCD gfx950).

#define H 512
#define W 512
#define NIMG 16
#define HW (H * W)
#define RW 5                       // exact window radius; certified + fallback
#define SEG 16                     // output rows per thread (cols kernel)
#define HALO (SEG + 2 * RW)        // 26 halo rows
#define JT 256                     // columns per block
#define NBLK (NIMG * (H / SEG) * (W / JT))   // 1024 blocks

static __device__ __forceinline__ float fast_exp2(float x) {
#if __has_builtin(__builtin_amdgcn_exp2f)
    return __builtin_amdgcn_exp2f(x);
#else
    return exp2f(x);
#endif
}
static __device__ __forceinline__ float fast_rcp(float x) {
#if __has_builtin(__builtin_amdgcn_rcpf)
    return __builtin_amdgcn_rcpf(x);
#else
    return 1.0f / x;
#endif
}

// ---------------------------------------------------------------------------
// Pass 1 (validated, absmax 0.0 five times): per-row 1D width-distance
// squared. One wave per row, 8 contiguous elements per lane.
// ---------------------------------------------------------------------------
__global__ __launch_bounds__(256) void edt_rows_kernel(const float* __restrict__ yt,
                                                       float* __restrict__ d1sq) {
    int wid = blockIdx.x * 4 + (threadIdx.x >> 6);
    int lane = threadIdx.x & 63;
    int img = wid >> 9;
    int row = wid & (H - 1);

    const float* rp = yt + ((size_t)img * H + row) * W;
    int k0 = lane * 8;
    float4 va = *reinterpret_cast<const float4*>(rp + k0);
    float4 vb = *reinterpret_cast<const float4*>(rp + k0 + 4);
    float g[8] = { va.x, va.y, va.z, va.w, vb.x, vb.y, vb.z, vb.w };
    const float INF = 1024.0f;
    #pragma unroll
    for (int t = 0; t < 8; ++t) g[t] = (g[t] > 0.5f) ? 0.0f : INF;

    const float BIG = 3.0e38f;
    float pm[8], sm[8];

    float run = BIG;
    #pragma unroll
    for (int t = 0; t < 8; ++t) {
        run = fminf(run, g[t] - (float)(k0 + t));
        pm[t] = run;
    }
    float incl = run;
    #pragma unroll
    for (int d = 1; d < 64; d <<= 1) {
        float o = __shfl_up(incl, d);
        if (lane >= d) incl = fminf(incl, o);
    }
    float excl = __shfl_up(incl, 1);
    if (lane == 0) excl = BIG;

    run = BIG;
    #pragma unroll
    for (int t = 7; t >= 0; --t) {
        run = fminf(run, g[t] + (float)(k0 + t));
        sm[t] = run;
    }
    float incl2 = run;
    #pragma unroll
    for (int d = 1; d < 64; d <<= 1) {
        float o = __shfl_down(incl2, d);
        if (lane < 64 - d) incl2 = fminf(incl2, o);
    }
    float excl2 = __shfl_down(incl2, 1);
    if (lane == 63) excl2 = BIG;

    float out[8];
    #pragma unroll
    for (int t = 0; t < 8; ++t) {
        float kf = (float)(k0 + t);
        float f = kf + fminf(excl, pm[t]);
        float b = -kf + fminf(excl2, sm[t]);
        float d = fminf(f, b);
        out[t] = d * d;              // exact integer in fp32
    }
    float* op = d1sq + (size_t)img * HW + (size_t)row * W + k0;
    *reinterpret_cast<float4*>(op)     = make_float4(out[0], out[1], out[2], out[3]);
    *reinterpret_cast<float4*>(op + 4) = make_float4(out[4], out[5], out[6], out[7]);
}

// ---------------------------------------------------------------------------
// Pass 2: LDS-free windowed exact column envelope + fused loss.
// Per thread: one column x SEG rows; HALO independent coalesced global loads.
// Window offsets are compile-time constants, paired symmetrically:
// min(w[-k],w[+k]) + k^2. Certification: window min <= (RW+1)^2 guarantees
// global optimality; else exact full-column fallback (dead for this input).
// Epilogue: softmax(2ch) == sigmoid -> 1 v_exp_f32 + 1 v_rcp_f32 per pixel.
// Per-block partial written with a PLAIN store; visibility via kernel boundary.
// ---------------------------------------------------------------------------
__global__ __launch_bounds__(256) void edt_cols_loss_kernel(
        const float* __restrict__ yp, const float* __restrict__ yt,
        const float* __restrict__ d1sq, double* __restrict__ part) {
    __shared__ double wsum[4];

    const int tid  = threadIdx.x;
    const int lane = tid & 63;
    const int wv   = tid >> 6;
    const int j    = blockIdx.x * JT + tid;
    const int i0   = blockIdx.y * SEG;
    const int img  = blockIdx.z;
    const int bid  = (blockIdx.z * gridDim.y + blockIdx.y) * gridDim.x + blockIdx.x;

    const float BIG = 3.0e38f;
    const float* dp = d1sq + (size_t)img * HW;

    float w[HALO];
    #pragma unroll
    for (int k = 0; k < HALO; ++k) {
        int ip = i0 - RW + k;
        w[k] = (ip >= 0 && ip < H) ? dp[ip * W + j] : BIG;
    }

    float mn[SEG];
    #pragma unroll
    for (int m = 0; m < SEG; ++m) {
        float a1 = fminf(w[m + 4], w[m + 6]) + 1.0f;
        float a2 = fminf(w[m + 3], w[m + 7]) + 4.0f;
        float a3 = fminf(w[m + 2], w[m + 8]) + 9.0f;
        float a4 = fminf(w[m + 1], w[m + 9]) + 16.0f;
        float a5 = fminf(w[m + 0], w[m + 10]) + 25.0f;
        mn[m] = fminf(fminf(fminf(w[m + 5], a1), fminf(a2, a3)), fminf(a4, a5));
    }

    bool need = false;
    #pragma unroll
    for (int m = 0; m < SEG; ++m) need |= (mn[m] > 36.0f);
    if (__any(need)) {          // exact fallback — provably dead for this input
        for (int ip = 0; ip < H; ++ip) {
            float v = dp[ip * W + j];
            #pragma unroll
            for (int m = 0; m < SEG; ++m) {
                int d = (i0 + m) - ip;
                mn[m] = fminf(mn[m], v + (float)(d * d));
            }
        }
    }

    // ---- fused loss epilogue: p = sigmoid(x_c - x_o) via exp2 + rcp ----
    const int n = img >> 1;
    const int c = img & 1;
    const float* ypc = yp + (size_t)(n * 2 + c) * HW;
    const float* ypo = yp + (size_t)(n * 2 + (1 - c)) * HW;
    const float* ytc = yt + (size_t)img * HW;
    const float LOG2E = 1.44269504088896340736f;

    double local = 0.0;
    #pragma unroll
    for (int m = 0; m < SEG; ++m) {
        int idx = (i0 + m) * W + j;
        float dmv = sqrtf(mn[m]) * (1.0f / 511.0f);
        float d  = ypo[idx] - ypc[idx];
        float e  = fast_exp2(d * LOG2E);
        float p  = fast_rcp(1.0f + e);
        float df = p - ytc[idx];
        local += (double)((1.0f + dmv) * (df * df));
    }

    #pragma unroll
    for (int d = 32; d > 0; d >>= 1) local += __shfl_down(local, d);
    if (lane == 0) wsum[wv] = local;
    __syncthreads();
    if (tid == 0)
        part[bid] = wsum[0] + wsum[1] + wsum[2] + wsum[3];   // plain store
}

// Sum the 1024 per-block partials and normalize.
__global__ __launch_bounds__(256) void finalize_kernel(const double* __restrict__ part,
                                                       float* __restrict__ out) {
    __shared__ double ws[4];
    int t = threadIdx.x;
    double v = part[t] + part[t + 256] + part[t + 512] + part[t + 768];
    #pragma unroll
    for (int d = 32; d > 0; d >>= 1) v += __shfl_down(v, d);
    if ((t & 63) == 0) ws[t >> 6] = v;
    __syncthreads();
    if (t == 0)
        out[0] = (float)((ws[0] + ws[1] + ws[2] + ws[3]) / (double)(NIMG * HW));
}

extern "C" void kernel_launch(void* const* d_in, const int* in_sizes, int n_in,
                              void* d_out, int out_size, void* d_ws, size_t ws_size,
                              hipStream_t stream) {
    const float* y_pred = (const float*)d_in[0];
    const float* y_true = (const float*)d_in[1];
    float* out = (float*)d_out;

    double* part = (double*)d_ws;                       // 1024 doubles
    float*  d1sq = (float*)((char*)d_ws + 16384);       // 16.8 MB

    edt_rows_kernel<<<dim3(NIMG * H / 4), 256, 0, stream>>>(y_true, d1sq);
    edt_cols_loss_kernel<<<dim3(W / JT, H / SEG, NIMG), 256, 0, stream>>>(
        y_pred, y_true, d1sq, part);
    finalize_kernel<<<1, 256, 0, stream>>>(part, out);
}